// Round 2
// baseline (1053.589 us; speedup 1.0000x reference)
//
#include <hip/hip_runtime.h>
#include <stdint.h>

// ---------------- types ----------------
typedef __attribute__((ext_vector_type(8))) short short8;   // 8 x bf16 MFMA A/B frag
typedef __attribute__((ext_vector_type(4))) short short4v;  // 8B packed LDS write
typedef __attribute__((ext_vector_type(4))) float float4v;  // MFMA C/D frag

__device__ __forceinline__ short f2bf(float f) {
  uint32_t u = __builtin_bit_cast(uint32_t, f);
  u += 0x7FFFu + ((u >> 16) & 1u);   // round-to-nearest-even
  return (short)(u >> 16);
}

#define MFMA __builtin_amdgcn_mfma_f32_16x16x32_bf16

// DIM=512, HEADS=8, D=64, N=64, B=2048 windows, MLON=64, PER_LAT=225
#define XPITCH 520   // 512+8 shorts: b128 row-stride pattern == contiguous class
#define QPITCH 72    // 64+8 shorts

// =====================================================================
// Kernel 1: convert weights to bf16 in workspace
// =====================================================================
__global__ void prep_weights(const float* __restrict__ wq, const float* __restrict__ wp,
                             short* __restrict__ wq_b, short* __restrict__ wp_b) {
  int i = blockIdx.x * blockDim.x + threadIdx.x;
  int stride = gridDim.x * blockDim.x;
  for (int j = i; j < 786432 / 4; j += stride) {
    float4 v = ((const float4*)wq)[j];
    short4v t = {f2bf(v.x), f2bf(v.y), f2bf(v.z), f2bf(v.w)};
    ((short4v*)wq_b)[j] = t;
  }
  for (int j = i; j < 262144 / 4; j += stride) {
    float4 v = ((const float4*)wp)[j];
    short4v t = {f2bf(v.x), f2bf(v.y), f2bf(v.z), f2bf(v.w)};
    ((short4v*)wp_b)[j] = t;
  }
}

// =====================================================================
// Fully fused: QKV GEMM + window attention + output projection.
// 1 block = 1 window. 512 threads = 8 waves. Per round (2 heads):
//   phase1: 8 jobs (Q64 x2, K64 x2, V32 x4), one per wave. 64/32-wide
//     output strips: X B/A-frags read once per job -> 2 MB LDS/block (was 6).
//   phase2: wave -> (head, 16-row strip): S = Q*K^T + analytic earth bias,
//     16-lane shfl softmax, P -> Qs (wave-local rows, no barrier), O = P*V
//     kept in registers as packed bf16 (Opk).
// After 4 rounds: O (64x512) -> dead Xs region; proj: wave w computes
// out[:, w*64 .. w*64+64) = O @ Wp^T + b, fp32 stores. No attn round-trip.
// =====================================================================
__global__ __launch_bounds__(512, 2)
void fused_attn(const float* __restrict__ x, const short* __restrict__ wq,
                const short* __restrict__ wp, const float* __restrict__ bqkv,
                const float* __restrict__ bproj, const float* __restrict__ btab,
                float* __restrict__ out) {
  __shared__ short Xs[64 * XPITCH];        // 66,560 B (X, later O)
  __shared__ short Qs[2][64 * QPITCH];     // 18,432 B
  __shared__ short Ks[2][64 * QPITCH];     // 18,432 B
  __shared__ short Vt[2][64 * QPITCH];     // 18,432 B   total 121,856 B

  const int b     = blockIdx.x;
  const int tid   = threadIdx.x;
  const int lane  = tid & 63;
  const int w     = tid >> 6;      // wave 0..7
  const int l16   = lane & 15;
  const int quad  = lane >> 4;     // 0..3
  const int lat   = b >> 6;        // MLON = 64
  const int hsel2 = w >> 2;        // phase2 head select
  const int n0    = (w & 3) * 16;  // phase2 row strip

  // ---- stage X window into LDS as bf16 ----
  const float* xw = x + (size_t)b * (64 * 512);
  for (int c = tid; c < 64 * 128; c += 512) {   // float4 chunks
    int n = c >> 7, kc = c & 127;
    float4 v = *(const float4*)(xw + n * 512 + kc * 4);
    short4v t = {f2bf(v.x), f2bf(v.y), f2bf(v.z), f2bf(v.w)};
    *(short4v*)&Xs[n * XPITCH + kc * 4] = t;
  }
  __syncthreads();

  short4v Opk[4][4];   // [round][t]: O rows n0+quad*4+i, cols head*64 + t*16 + l16

#pragma unroll
  for (int r = 0; r < 4; ++r) {
    const int h0 = 2 * r;
    // ---------------- phase 1: QKV, 8 jobs ----------------
    if (w < 4) {
      // Q/K transposed GEMM, 64-wide: out[d][n] = sum_k W[.,k] X[n,k]
      const int mat = w >> 1;          // 0=Q, 1=K
      const int hs  = w & 1;
      const int h   = h0 + hs;
      const short* Wb = wq + (size_t)(mat * 512 + h * 64) * 512;
      float4v acc[4][4] = {};
      for (int kk = 0; kk < 512; kk += 32) {
        short8 a[4], bb[4];
#pragma unroll
        for (int ti = 0; ti < 4; ++ti)
          a[ti] = *(const short8*)(Wb + (ti * 16 + l16) * 512 + kk + quad * 8);
#pragma unroll
        for (int tj = 0; tj < 4; ++tj)
          bb[tj] = *(const short8*)&Xs[(tj * 16 + l16) * XPITCH + kk + quad * 8];
#pragma unroll
        for (int ti = 0; ti < 4; ++ti)
#pragma unroll
          for (int tj = 0; tj < 4; ++tj)
            acc[ti][tj] = MFMA(a[ti], bb[tj], acc[ti][tj], 0, 0, 0);
      }
      short* dst = (mat == 0) ? &Qs[hs][0] : &Ks[hs][0];
      const float scale = (mat == 0) ? 0.125f : 1.0f;   // fold q-scale (exact pow2)
#pragma unroll
      for (int ti = 0; ti < 4; ++ti) {
        float bias[4];
#pragma unroll
        for (int i = 0; i < 4; ++i)
          bias[i] = bqkv[mat * 512 + h * 64 + ti * 16 + quad * 4 + i];
#pragma unroll
        for (int tj = 0; tj < 4; ++tj) {
          short4v pk;   // d = ti*16+quad*4+i, n = tj*16+l16 -> [n][d] packed
#pragma unroll
          for (int i = 0; i < 4; ++i) pk[i] = f2bf((acc[ti][tj][i] + bias[i]) * scale);
          *(short4v*)&dst[(tj * 16 + l16) * QPITCH + ti * 16 + quad * 4] = pk;
        }
      }
    } else {
      // V GEMM, 32-wide: out[m][d] = sum_k X[m,k] W[.,k]
      const int hs = (w >> 1) & 1;
      const int h  = h0 + hs;
      const int d0 = (w & 1) * 32;
      const short* Wb = wq + (size_t)(1024 + h * 64 + d0) * 512;
      float4v acc[4][2] = {};
      for (int kk = 0; kk < 512; kk += 32) {
        short8 a[4], bb[2];
#pragma unroll
        for (int ti = 0; ti < 4; ++ti)
          a[ti] = *(const short8*)&Xs[(ti * 16 + l16) * XPITCH + kk + quad * 8];
#pragma unroll
        for (int tj = 0; tj < 2; ++tj)
          bb[tj] = *(const short8*)(Wb + (tj * 16 + l16) * 512 + kk + quad * 8);
#pragma unroll
        for (int ti = 0; ti < 4; ++ti)
#pragma unroll
          for (int tj = 0; tj < 2; ++tj)
            acc[ti][tj] = MFMA(a[ti], bb[tj], acc[ti][tj], 0, 0, 0);
      }
#pragma unroll
      for (int tj = 0; tj < 2; ++tj) {
        float bias = bqkv[1024 + h * 64 + d0 + tj * 16 + l16];
#pragma unroll
        for (int ti = 0; ti < 4; ++ti) {
          short4v pk;   // m = ti*16+quad*4+i, d = d0+tj*16+l16 -> [d][m] packed
#pragma unroll
          for (int i = 0; i < 4; ++i) pk[i] = f2bf(acc[ti][tj][i] + bias);
          *(short4v*)&Vt[hs][(d0 + tj * 16 + l16) * QPITCH + ti * 16 + quad * 4] = pk;
        }
      }
    }
    __syncthreads();

    // ---------------- phase 2: attention ----------------
    {
      const int h = h0 + hsel2;

      // S = Q * K^T  (K-dim = d = 64)
      float4v s4[4] = {};
#pragma unroll
      for (int kd = 0; kd < 64; kd += 32) {
        short8 a = *(const short8*)&Qs[hsel2][(n0 + l16) * QPITCH + kd + quad * 8];
#pragma unroll
        for (int t = 0; t < 4; ++t) {
          short8 bf = *(const short8*)&Ks[hsel2][(t * 16 + l16) * QPITCH + kd + quad * 8];
          s4[t] = MFMA(a, bf, s4[t], 0, 0, 0);
        }
      }
      // analytic earth bias (skips rel_idx input entirely)
#pragma unroll
      for (int t = 0; t < 4; ++t) {
        int m = t * 16 + l16;
#pragma unroll
        for (int i = 0; i < 4; ++i) {
          int n = n0 + quad * 4 + i;
          int idx = ((n >> 3) - (m >> 3) + 7) * 15 + ((n & 7) - (m & 7) + 7) + lat * 225;
          s4[t][i] += btab[idx * 8 + h];
        }
      }
      // row softmax across 16 lanes x 4 regs
      float p[4][4];
#pragma unroll
      for (int i = 0; i < 4; ++i) {
        float mx = fmaxf(fmaxf(s4[0][i], s4[1][i]), fmaxf(s4[2][i], s4[3][i]));
        mx = fmaxf(mx, __shfl_xor(mx, 1));
        mx = fmaxf(mx, __shfl_xor(mx, 2));
        mx = fmaxf(mx, __shfl_xor(mx, 4));
        mx = fmaxf(mx, __shfl_xor(mx, 8));
        float e0 = __expf(s4[0][i] - mx), e1 = __expf(s4[1][i] - mx);
        float e2 = __expf(s4[2][i] - mx), e3 = __expf(s4[3][i] - mx);
        float sm = e0 + e1 + e2 + e3;
        sm += __shfl_xor(sm, 1);
        sm += __shfl_xor(sm, 2);
        sm += __shfl_xor(sm, 4);
        sm += __shfl_xor(sm, 8);
        float inv = 1.0f / sm;
        p[0][i] = e0 * inv; p[1][i] = e1 * inv; p[2][i] = e2 * inv; p[3][i] = e3 * inv;
      }
      // P -> own Qs rows (wave-local; NO barrier needed)
#pragma unroll
      for (int t = 0; t < 4; ++t)
#pragma unroll
        for (int i = 0; i < 4; ++i)
          Qs[hsel2][(n0 + quad * 4 + i) * QPITCH + t * 16 + l16] = f2bf(p[t][i]);

      // O = P * V  (K-dim = m = 64), keep in registers as packed bf16
      float4v o4[4] = {};
#pragma unroll
      for (int km = 0; km < 64; km += 32) {
        short8 a = *(const short8*)&Qs[hsel2][(n0 + l16) * QPITCH + km + quad * 8];
#pragma unroll
        for (int t = 0; t < 4; ++t) {
          short8 bf = *(const short8*)&Vt[hsel2][(t * 16 + l16) * QPITCH + km + quad * 8];
          o4[t] = MFMA(a, bf, o4[t], 0, 0, 0);
        }
      }
#pragma unroll
      for (int t = 0; t < 4; ++t) {
        short4v pk;
#pragma unroll
        for (int i = 0; i < 4; ++i) pk[i] = f2bf(o4[t][i]);
        Opk[r][t] = pk;
      }
    }
    __syncthreads();   // slabs reused next round
  }

  // ---- O (all 8 heads) -> Xs region, [n][c] layout ----
#pragma unroll
  for (int r = 0; r < 4; ++r) {
    const int cb = (2 * r + hsel2) * 64;
#pragma unroll
    for (int t = 0; t < 4; ++t)
#pragma unroll
      for (int i = 0; i < 4; ++i)
        Xs[(n0 + quad * 4 + i) * XPITCH + cb + t * 16 + l16] = Opk[r][t][i];
  }
  __syncthreads();

  // ---- proj: wave w -> out cols [w*64, w*64+64) ----
  {
    const short* Wp = wp + (size_t)(w * 64) * 512;
    float4v acc[4][4] = {};
    for (int kk = 0; kk < 512; kk += 32) {
      short8 a[4], bb[4];
#pragma unroll
      for (int ti = 0; ti < 4; ++ti)
        a[ti] = *(const short8*)&Xs[(ti * 16 + l16) * XPITCH + kk + quad * 8];
#pragma unroll
      for (int tj = 0; tj < 4; ++tj)
        bb[tj] = *(const short8*)(Wp + (tj * 16 + l16) * 512 + kk + quad * 8);
#pragma unroll
      for (int ti = 0; ti < 4; ++ti)
#pragma unroll
        for (int tj = 0; tj < 4; ++tj)
          acc[ti][tj] = MFMA(a[ti], bb[tj], acc[ti][tj], 0, 0, 0);
    }
    float bj[4];
#pragma unroll
    for (int tj = 0; tj < 4; ++tj) bj[tj] = bproj[w * 64 + tj * 16 + l16];
    float* ob = out + (size_t)b * (64 * 512);
#pragma unroll
    for (int ti = 0; ti < 4; ++ti)
#pragma unroll
      for (int i = 0; i < 4; ++i) {
        const int row = (ti * 16 + quad * 4 + i) * 512;
#pragma unroll
        for (int tj = 0; tj < 4; ++tj)
          ob[row + w * 64 + tj * 16 + l16] = acc[ti][tj][i] + bj[tj];
      }
  }
}

// =====================================================================
extern "C" void kernel_launch(void* const* d_in, const int* in_sizes, int n_in,
                              void* d_out, int out_size, void* d_ws, size_t ws_size,
                              hipStream_t stream) {
  const float* x     = (const float*)d_in[0];   // (2048, 64, 512)
  const float* wqkv  = (const float*)d_in[1];   // (1536, 512)
  const float* bqkv  = (const float*)d_in[2];   // (1536,)
  const float* wproj = (const float*)d_in[3];   // (512, 512)
  const float* bproj = (const float*)d_in[4];   // (512,)
  const float* btab  = (const float*)d_in[5];   // (7200, 8)
  // d_in[6] = rel_idx -- recomputed analytically in-kernel, not read.
  float* out = (float*)d_out;

  short* wq_b = (short*)d_ws;            // 786,432 bf16
  short* wp_b = wq_b + 786432;           // 262,144 bf16

  prep_weights<<<256, 256, 0, stream>>>(wqkv, wproj, wq_b, wp_b);
  fused_attn<<<2048, 512, 0, stream>>>(x, wq_b, wp_b, bqkv, bproj, btab, out);
}